// Round 2
// baseline (183.581 us; speedup 1.0000x reference)
//
#include <hip/hip_runtime.h>

#define NCH 5  // thermostat chain length (C) — fixed by the problem

// ---------------------------------------------------------------------------
// Kernel 1: per-batch kinetic-energy reduction  KE_b = sum_{n,d} mom^2 / mas
// Layout: mom is (B, N, 3) contiguous, mas is (B, N). Each thread handles 4
// atoms = 12 mom floats (3x float4) + 4 mas floats (1x float4) = 64 B/lane.
// Block partials go to d_ws (deterministic; no atomics, no zero-init needed).
// ---------------------------------------------------------------------------
__global__ __launch_bounds__(256) void nhc_reduce(
    const float* __restrict__ mom, const float* __restrict__ mas,
    float* __restrict__ partials, int n_atoms, int groups_per_batch,
    int blocks_per_batch)
{
    const int b = blockIdx.y;
    const int t = blockIdx.x * blockDim.x + threadIdx.x;  // 4-atom group idx

    float s = 0.0f;
    if (t < groups_per_batch) {
        const float4* mom4 = (const float4*)(mom + (size_t)b * n_atoms * 3);
        const float4* mas4 = (const float4*)(mas + (size_t)b * n_atoms);
        float4 p0 = mom4[3 * t + 0];
        float4 p1 = mom4[3 * t + 1];
        float4 p2 = mom4[3 * t + 2];
        float4 m  = mas4[t];
        s = (p0.x * p0.x + p0.y * p0.y + p0.z * p0.z) / m.x
          + (p0.w * p0.w + p1.x * p1.x + p1.y * p1.y) / m.y
          + (p1.z * p1.z + p1.w * p1.w + p2.x * p2.x) / m.z
          + (p2.y * p2.y + p2.z * p2.z + p2.w * p2.w) / m.w;
    }

    // wave(64) shuffle reduction, then 4 wave partials via LDS
    #pragma unroll
    for (int off = 32; off > 0; off >>= 1) s += __shfl_down(s, off, 64);
    __shared__ float lds[4];
    const int lane = threadIdx.x & 63, wv = threadIdx.x >> 6;
    if (lane == 0) lds[wv] = s;
    __syncthreads();
    if (threadIdx.x == 0)
        partials[(size_t)b * blocks_per_batch + blockIdx.x] =
            lds[0] + lds[1] + lds[2] + lds[3];
}

// ---------------------------------------------------------------------------
// Kernel 2: the entire 2x7 Suzuki-Yoshida substep loop as per-batch scalar
// math. One thread per batch. KE evolves as ke *= s^2 (exact algebraic
// identity for g0 under uniform momentum rescaling). Emits pos_nhc, mom_nhc
// and the cumulative momentum scale S_b.
// ---------------------------------------------------------------------------
__global__ void nhc_chain(
    const float* __restrict__ partials, int blocks_per_batch,
    const float* __restrict__ kbt, const float* __restrict__ dtm,
    const float* __restrict__ pos_nhc, const float* __restrict__ mom_nhc,
    const float* __restrict__ mas_nhc, const float* __restrict__ stp,
    float* __restrict__ out_posnhc, float* __restrict__ out_momnhc,
    float* __restrict__ scales, int B, float dof)
{
    const int b = blockIdx.x * blockDim.x + threadIdx.x;
    if (b >= B) return;

    // Deterministic sequential sum of this batch's block partials.
    float ke = 0.0f;
    for (int i = 0; i < blocks_per_batch; ++i)
        ke += partials[(size_t)b * blocks_per_batch + i];

    // 7-point Suzuki-Yoshida weights (double-computed, f32-cast like JAX).
    constexpr double W1 = 0.78451361047756;
    constexpr double W2 = 0.235573213359357;
    constexpr double W3 = -1.17767998417887;
    constexpr double W4 = 1.0 - 2.0 * (W1 + W2 + W3);
    const float syw[7] = {(float)W1, (float)W2, (float)W3, (float)W4,
                          (float)W3, (float)W2, (float)W1};

    const float kb = kbt[b], dt = dtm[b], st = stp[0];
    float pnh[NCH], mnh[NCH], qn[NCH];
    #pragma unroll
    for (int c = 0; c < NCH; ++c) {
        pnh[c] = pos_nhc[b * NCH + c];
        mnh[c] = mom_nhc[b * NCH + c];
        qn[c]  = mas_nhc[b * NCH + c];
    }

    float Scum = 1.0f;
    for (int r = 0; r < 14; ++r) {            // NRESPA(2) x 7 SY weights
        const float w   = syw[r % 7];
        const float dea = dt * (st * w * 0.5f);   // dtm * (stp*w/NRESPA)
        const float de2 = dea * 0.5f;
        const float de4 = dea * 0.25f;

        float g[NCH], mc[NCH];
        g[0] = ke - kb * dof;
        #pragma unroll
        for (int j = 1; j < NCH; ++j)
            g[j] = mnh[j - 1] * mnh[j - 1] / qn[j - 1] - kb;
        #pragma unroll
        for (int c = 0; c < NCH; ++c) mc[c] = mnh[c];

        // first half-kick + chain pass (uses pre-step g)
        mc[NCH - 1] += g[NCH - 1] * de2;
        #pragma unroll
        for (int j = NCH - 2; j >= 0; --j) {
            const float f = expf(-mc[j + 1] / qn[j + 1] * de4);
            mc[j] = (mc[j] * f + g[j] * de2) * f;
        }

        // chain-position drift + atomic-momentum rescale
        #pragma unroll
        for (int c = 0; c < NCH; ++c) pnh[c] += mc[c] / qn[c] * dea;
        const float s = expf(-mc[0] / qn[0] * dea);
        Scum *= s;
        ke   *= s * s;   // sum((s*mom)^2/mas) == s^2 * KE

        // second half: g recomputed with rescaled KE but ORIGINAL chain
        // momenta (mnh untouched so g[1..] unchanged) — faithful to source.
        g[0] = ke - kb * dof;
        #pragma unroll
        for (int j = NCH - 2; j >= 0; --j) {
            const float f = expf(-mc[j + 1] / qn[j + 1] * de4);
            mc[j] = (mc[j] * f + g[j] * de2) * f;
        }
        mc[NCH - 1] += g[NCH - 1] * de2;

        #pragma unroll
        for (int c = 0; c < NCH; ++c) mnh[c] = mc[c];
    }

    #pragma unroll
    for (int c = 0; c < NCH; ++c) {
        out_posnhc[b * NCH + c] = pnh[c];
        out_momnhc[b * NCH + c] = mnh[c];
    }
    scales[b] = Scum;
}

// ---------------------------------------------------------------------------
// Kernel 3: mom_out = mom_in * S_b   (float4 streaming)
// ---------------------------------------------------------------------------
__global__ __launch_bounds__(256) void nhc_scale(
    const float* __restrict__ mom, float* __restrict__ out,
    const float* __restrict__ scales, int n4_per_batch)
{
    const int b = blockIdx.y;
    const int i = blockIdx.x * blockDim.x + threadIdx.x;
    if (i >= n4_per_batch) return;
    const float s = scales[b];
    const float4* in4 = (const float4*)mom + (size_t)b * n4_per_batch;
    float4*       o4  = (float4*)out       + (size_t)b * n4_per_batch;
    float4 v = in4[i];
    v.x *= s; v.y *= s; v.z *= s; v.w *= s;
    o4[i] = v;
}

extern "C" void kernel_launch(void* const* d_in, const int* in_sizes, int n_in,
                              void* d_out, int out_size, void* d_ws, size_t ws_size,
                              hipStream_t stream) {
    // input order: pos(0, unused), mom(1), mas(2), kbt(3), dtm(4),
    //              pos_nhc(5), mom_nhc(6), mas_nhc(7), stp(8)
    const float* mom     = (const float*)d_in[1];
    const float* mas     = (const float*)d_in[2];
    const float* kbt     = (const float*)d_in[3];
    const float* dtm     = (const float*)d_in[4];
    const float* pos_nhc = (const float*)d_in[5];
    const float* mom_nhc = (const float*)d_in[6];
    const float* mas_nhc = (const float*)d_in[7];
    const float* stp     = (const float*)d_in[8];

    const int B  = in_sizes[3];            // 32
    const int ND = in_sizes[1] / B;        // N*D = 393216
    const int N  = in_sizes[2] / B;        // 131072 atoms
    (void)n_in; (void)ws_size; (void)out_size;
    const float dof = (float)ND;

    const int groups_per_batch = N / 4;                          // 32768
    const int blocks_per_batch = (groups_per_batch + 255) / 256; // 128

    float* partials = (float*)d_ws;                       // B*128 floats
    float* scales   = partials + (size_t)B * blocks_per_batch;

    float* out_f       = (float*)d_out;
    float* out_posnhc  = out_f + (size_t)B * ND;
    float* out_momnhc  = out_posnhc + (size_t)B * NCH;

    nhc_reduce<<<dim3(blocks_per_batch, B), 256, 0, stream>>>(
        mom, mas, partials, N, groups_per_batch, blocks_per_batch);

    nhc_chain<<<1, 64, 0, stream>>>(
        partials, blocks_per_batch, kbt, dtm, pos_nhc, mom_nhc, mas_nhc, stp,
        out_posnhc, out_momnhc, scales, B, dof);

    const int n4 = ND / 4;                                // 98304
    nhc_scale<<<dim3((n4 + 255) / 256, B), 256, 0, stream>>>(
        mom, out_f, scales, n4);
}

// Round 3
// 178.217 us; speedup vs baseline: 1.0301x; 1.0301x over previous
//
#include <hip/hip_runtime.h>

#define NCH 5  // thermostat chain length (C) — fixed by the problem

// ---------------------------------------------------------------------------
// Kernel 1: per-batch kinetic-energy reduction  KE_b = sum_{n,d} mom^2 / mas
// mom is (B, N, 3) contiguous, mas is (B, N). Each thread: 4 atoms =
// 3x float4 mom + 1x float4 mas = 64 B/lane. Deterministic block partials.
// ---------------------------------------------------------------------------
__global__ __launch_bounds__(256) void nhc_reduce(
    const float* __restrict__ mom, const float* __restrict__ mas,
    float* __restrict__ partials, int n_atoms, int groups_per_batch,
    int blocks_per_batch)
{
    const int b = blockIdx.y;
    const int t = blockIdx.x * blockDim.x + threadIdx.x;  // 4-atom group idx

    float s = 0.0f;
    if (t < groups_per_batch) {
        const float4* mom4 = (const float4*)(mom + (size_t)b * n_atoms * 3);
        const float4* mas4 = (const float4*)(mas + (size_t)b * n_atoms);
        float4 p0 = mom4[3 * t + 0];
        float4 p1 = mom4[3 * t + 1];
        float4 p2 = mom4[3 * t + 2];
        float4 m  = mas4[t];
        s = (p0.x * p0.x + p0.y * p0.y + p0.z * p0.z) / m.x
          + (p0.w * p0.w + p1.x * p1.x + p1.y * p1.y) / m.y
          + (p1.z * p1.z + p1.w * p1.w + p2.x * p2.x) / m.z
          + (p2.y * p2.y + p2.z * p2.z + p2.w * p2.w) / m.w;
    }

    #pragma unroll
    for (int off = 32; off > 0; off >>= 1) s += __shfl_down(s, off, 64);
    __shared__ float lds[4];
    const int lane = threadIdx.x & 63, wv = threadIdx.x >> 6;
    if (lane == 0) lds[wv] = s;
    __syncthreads();
    if (threadIdx.x == 0)
        partials[(size_t)b * blocks_per_batch + blockIdx.x] =
            lds[0] + lds[1] + lds[2] + lds[3];
}

// ---------------------------------------------------------------------------
// Kernel 2 (fused chain + scale): every block redundantly computes its
// batch's 14-substep SY chain from the reduce partials (wave-0 prelude,
// ~1-2 us, bit-identical across blocks), broadcasts the cumulative momentum
// scale via LDS, then stream-scales its slice of mom. Removes the serialized
// single-block chain kernel + one launch + the scales[] round-trip.
// blockIdx.x == 0 additionally writes pos_nhc / mom_nhc outputs.
// ---------------------------------------------------------------------------
__global__ __launch_bounds__(256) void nhc_chain_scale(
    const float* __restrict__ mom, const float* __restrict__ partials,
    const float* __restrict__ kbt, const float* __restrict__ dtm,
    const float* __restrict__ pos_nhc, const float* __restrict__ mom_nhc,
    const float* __restrict__ mas_nhc, const float* __restrict__ stp,
    float* __restrict__ out_mom, float* __restrict__ out_posnhc,
    float* __restrict__ out_momnhc,
    int bpb_red, int n4_per_batch, float dof)
{
    const int b = blockIdx.y;
    __shared__ float s_scale;

    if (threadIdx.x < 64) {
        const int lane = threadIdx.x;
        // deterministic: fixed assignment lane -> partials, fixed butterfly
        float ke = 0.0f;
        for (int i = lane; i < bpb_red; i += 64)
            ke += partials[(size_t)b * bpb_red + i];
        #pragma unroll
        for (int off = 32; off > 0; off >>= 1) ke += __shfl_down(ke, off, 64);

        if (lane == 0) {
            constexpr double W1 = 0.78451361047756;
            constexpr double W2 = 0.235573213359357;
            constexpr double W3 = -1.17767998417887;
            constexpr double W4 = 1.0 - 2.0 * (W1 + W2 + W3);
            const float syw[7] = {(float)W1, (float)W2, (float)W3, (float)W4,
                                  (float)W3, (float)W2, (float)W1};

            const float kb = kbt[b], dt = dtm[b], st = stp[0];
            float pnh[NCH], mnh[NCH], qn[NCH];
            #pragma unroll
            for (int c = 0; c < NCH; ++c) {
                pnh[c] = pos_nhc[b * NCH + c];
                mnh[c] = mom_nhc[b * NCH + c];
                qn[c]  = mas_nhc[b * NCH + c];
            }

            float Scum = 1.0f;
            for (int r = 0; r < 14; ++r) {        // NRESPA(2) x 7 SY weights
                const float w   = syw[r % 7];
                const float dea = dt * (st * w * 0.5f);
                const float de2 = dea * 0.5f;
                const float de4 = dea * 0.25f;

                float g[NCH], mc[NCH];
                g[0] = ke - kb * dof;
                #pragma unroll
                for (int j = 1; j < NCH; ++j)
                    g[j] = mnh[j - 1] * mnh[j - 1] / qn[j - 1] - kb;
                #pragma unroll
                for (int c = 0; c < NCH; ++c) mc[c] = mnh[c];

                // first half-kick + chain pass (pre-step g)
                mc[NCH - 1] += g[NCH - 1] * de2;
                #pragma unroll
                for (int j = NCH - 2; j >= 0; --j) {
                    const float f = expf(-mc[j + 1] / qn[j + 1] * de4);
                    mc[j] = (mc[j] * f + g[j] * de2) * f;
                }

                // drift + momentum rescale (carried algebraically on ke)
                #pragma unroll
                for (int c = 0; c < NCH; ++c) pnh[c] += mc[c] / qn[c] * dea;
                const float s = expf(-mc[0] / qn[0] * dea);
                Scum *= s;
                ke   *= s * s;   // sum((s*mom)^2/mas) == s^2 * KE

                // second half: g0 from rescaled KE; g[1..] unchanged
                g[0] = ke - kb * dof;
                #pragma unroll
                for (int j = NCH - 2; j >= 0; --j) {
                    const float f = expf(-mc[j + 1] / qn[j + 1] * de4);
                    mc[j] = (mc[j] * f + g[j] * de2) * f;
                }
                mc[NCH - 1] += g[NCH - 1] * de2;

                #pragma unroll
                for (int c = 0; c < NCH; ++c) mnh[c] = mc[c];
            }

            s_scale = Scum;
            if (blockIdx.x == 0) {
                #pragma unroll
                for (int c = 0; c < NCH; ++c) {
                    out_posnhc[b * NCH + c] = pnh[c];
                    out_momnhc[b * NCH + c] = mnh[c];
                }
            }
        }
    }
    __syncthreads();

    const float s = s_scale;
    const float4* in4 = (const float4*)mom + (size_t)b * n4_per_batch;
    float4*       o4  = (float4*)out_mom   + (size_t)b * n4_per_batch;
    const int stride = gridDim.x * blockDim.x;
    for (int i = blockIdx.x * blockDim.x + threadIdx.x; i < n4_per_batch;
         i += stride) {
        float4 v = in4[i];
        v.x *= s; v.y *= s; v.z *= s; v.w *= s;
        o4[i] = v;
    }
}

extern "C" void kernel_launch(void* const* d_in, const int* in_sizes, int n_in,
                              void* d_out, int out_size, void* d_ws, size_t ws_size,
                              hipStream_t stream) {
    // input order: pos(0, unused), mom(1), mas(2), kbt(3), dtm(4),
    //              pos_nhc(5), mom_nhc(6), mas_nhc(7), stp(8)
    const float* mom     = (const float*)d_in[1];
    const float* mas     = (const float*)d_in[2];
    const float* kbt     = (const float*)d_in[3];
    const float* dtm     = (const float*)d_in[4];
    const float* pos_nhc = (const float*)d_in[5];
    const float* mom_nhc = (const float*)d_in[6];
    const float* mas_nhc = (const float*)d_in[7];
    const float* stp     = (const float*)d_in[8];

    const int B  = in_sizes[3];            // 32
    const int ND = in_sizes[1] / B;        // N*D = 393216
    const int N  = in_sizes[2] / B;        // 131072 atoms
    (void)n_in; (void)ws_size; (void)out_size;
    const float dof = (float)ND;

    const int groups_per_batch = N / 4;                          // 32768
    const int blocks_per_batch = (groups_per_batch + 255) / 256; // 128

    float* partials = (float*)d_ws;                       // B*128 floats

    float* out_f       = (float*)d_out;
    float* out_posnhc  = out_f + (size_t)B * ND;
    float* out_momnhc  = out_posnhc + (size_t)B * NCH;

    nhc_reduce<<<dim3(blocks_per_batch, B), 256, 0, stream>>>(
        mom, mas, partials, N, groups_per_batch, blocks_per_batch);

    // 64 blocks/batch * 32 batches = 2048 blocks; 6 float4 per thread.
    const int n4 = ND / 4;                                // 98304
    nhc_chain_scale<<<dim3(64, B), 256, 0, stream>>>(
        mom, partials, kbt, dtm, pos_nhc, mom_nhc, mas_nhc, stp,
        out_f, out_posnhc, out_momnhc, blocks_per_batch, n4, dof);
}